// Round 3
// baseline (446.414 us; speedup 1.0000x reference)
//
#include <hip/hip_runtime.h>

// Problem constants: B=16, C=64, H=128, W=128, bchw layout, HW = 16384
// Output: fp32. Q/K/V staged as bf16 in ws. Attention via mfma_f32_16x16x32_bf16.
// Projections via mfma_f32_16x16x32_f16 (fp16 inputs, fp32 accum).
// This round: one mega proj dispatch (all jobs), and (if ws permits 6 QKV
// buffers) a single dual-branch attention dispatch that overlaps branch-2
// loads with branch-1 compute and writes io exactly once.
#define HW 16384
#define NE 16777216ull   // B*C*H*W

typedef short bf16x8 __attribute__((ext_vector_type(8)));
typedef _Float16 f16x8 __attribute__((ext_vector_type(8)));
typedef float f32x4  __attribute__((ext_vector_type(4)));

__device__ __forceinline__ unsigned short f2bf(float f) {
    unsigned int u = __float_as_uint(f);
    unsigned int r = (u + 0x7FFFu + ((u >> 16) & 1u)) >> 16;  // RNE
    return (unsigned short)r;
}

// ---------------------------------------------------------------------------
// Mega projection dispatch. Grid = njobs*1024 blocks; job = blockIdx.x>>10:
//   job 0: rA -> (qw,qb) -> QA            job 2: rB -> (qw,qb) -> QB
//   job 1: xA -> (kw,kb)->KA, (vw,vb)->VA job 3: xB -> (kw,kb)->KB, (vw,vb)->VB
// One block = one b, 256-wide hw tile; 256 threads = 4 waves.
// LDS xT[n][c] fp16 (transposed input tile), XOR-chunk swizzled; reused as
// obuf[64][256] bf16 for the coalesced dwordx4 store epilogue.
// Block 0 zeroes stats[0..127] when stats != null.
// ---------------------------------------------------------------------------
__global__ __launch_bounds__(256)
void proj_mfma_kernel(const float* __restrict__ rA, const float* __restrict__ xA,
                      const float* __restrict__ rB, const float* __restrict__ xB,
                      const float* __restrict__ qw, const float* __restrict__ qb,
                      const float* __restrict__ kw, const float* __restrict__ kb,
                      const float* __restrict__ vw, const float* __restrict__ vb,
                      unsigned short* __restrict__ QA, unsigned short* __restrict__ KA,
                      unsigned short* __restrict__ VA,
                      unsigned short* __restrict__ QB, unsigned short* __restrict__ KB,
                      unsigned short* __restrict__ VB,
                      float* __restrict__ stats) {
    __shared__ __align__(16) _Float16 xT[256 * 64];  // 32 KB
    unsigned short* obuf = reinterpret_cast<unsigned short*>(xT);
    int tid = threadIdx.x;
    if (stats != nullptr && blockIdx.x == 0 && tid < 128) stats[tid] = 0.f;

    int job = blockIdx.x >> 10;
    const float *in, *w1, *b1, *w2 = nullptr, *b2 = nullptr;
    unsigned short *o1, *o2 = nullptr;
    if (job == 0)      { in = rA; w1 = qw; b1 = qb; o1 = QA; }
    else if (job == 1) { in = xA; w1 = kw; b1 = kb; o1 = KA; w2 = vw; b2 = vb; o2 = VA; }
    else if (job == 2) { in = rB; w1 = qw; b1 = qb; o1 = QB; }
    else               { in = xB; w1 = kw; b1 = kb; o1 = KB; w2 = vw; b2 = vb; o2 = VB; }

    int pbase = (blockIdx.x & 1023) * 256;
    int b = pbase >> 14;
    int hw0 = pbase & 16383;
    const float* inb = in + (size_t)b * (64 * HW);

    // ---- stage transposed tile: thread t owns column n = t ----
    {
        int n = tid;
        int swz = n & 7;
        const float* colp = inb + hw0 + n;
#pragma unroll
        for (int kc = 0; kc < 8; ++kc) {
            f16x8 ev;
#pragma unroll
            for (int j = 0; j < 8; ++j)
                ev[j] = (_Float16)colp[(kc * 8 + j) * HW];
            *reinterpret_cast<f16x8*>(&xT[n * 64 + ((kc ^ swz) * 8)]) = ev;
        }
    }

    int lane = tid & 63;
    int wv = tid >> 6;
    int quad = lane >> 4;
    int m16 = lane & 15;
    int mb = wv * 16;
    int sw = m16 & 7;
    int hasw2 = (w2 != nullptr);

    // ---- A-frags (weights, fp16) + bias (overlaps with staging latency) ----
    f16x8 a1[2], a2[2];
    float bias1[4], bias2[4];
#pragma unroll
    for (int ks = 0; ks < 2; ++ks) {
        const float* wr = w1 + (mb + m16) * 64 + (ks * 4 + quad) * 8;
        f16x8 ev;
#pragma unroll
        for (int j = 0; j < 8; ++j) ev[j] = (_Float16)wr[j];
        a1[ks] = ev;
    }
#pragma unroll
    for (int r = 0; r < 4; ++r) bias1[r] = b1[mb + quad * 4 + r];
    if (hasw2) {
#pragma unroll
        for (int ks = 0; ks < 2; ++ks) {
            const float* wr = w2 + (mb + m16) * 64 + (ks * 4 + quad) * 8;
            f16x8 ev;
#pragma unroll
            for (int j = 0; j < 8; ++j) ev[j] = (_Float16)wr[j];
            a2[ks] = ev;
        }
#pragma unroll
        for (int r = 0; r < 4; ++r) bias2[r] = b2[mb + quad * 4 + r];
    }
    __syncthreads();

    unsigned short* o1b = o1 + (size_t)b * (64 * HW);
    unsigned short* o2b = hasw2 ? (o2 + (size_t)b * (64 * HW)) : o1b;

    // ---- D[o][n] = sum_c W[o][c] * xT[n][c]; results packed to bf16 pairs ----
    unsigned int pk1[32], pk2[32];
#pragma unroll
    for (int nt = 0; nt < 16; ++nt) {
        int row = nt * 16 + m16;
        f16x8 bF0 = *reinterpret_cast<const f16x8*>(&xT[row * 64 + ((quad ^ sw) * 8)]);
        f16x8 bF1 = *reinterpret_cast<const f16x8*>(&xT[row * 64 + (((4 + quad) ^ sw) * 8)]);
        f32x4 acc1 = {bias1[0], bias1[1], bias1[2], bias1[3]};
        acc1 = __builtin_amdgcn_mfma_f32_16x16x32_f16(a1[0], bF0, acc1, 0, 0, 0);
        acc1 = __builtin_amdgcn_mfma_f32_16x16x32_f16(a1[1], bF1, acc1, 0, 0, 0);
        pk1[nt * 2 + 0] = (unsigned int)f2bf(acc1[0]) | ((unsigned int)f2bf(acc1[1]) << 16);
        pk1[nt * 2 + 1] = (unsigned int)f2bf(acc1[2]) | ((unsigned int)f2bf(acc1[3]) << 16);
        if (hasw2) {
            f32x4 acc2 = {bias2[0], bias2[1], bias2[2], bias2[3]};
            acc2 = __builtin_amdgcn_mfma_f32_16x16x32_f16(a2[0], bF0, acc2, 0, 0, 0);
            acc2 = __builtin_amdgcn_mfma_f32_16x16x32_f16(a2[1], bF1, acc2, 0, 0, 0);
            pk2[nt * 2 + 0] = (unsigned int)f2bf(acc2[0]) | ((unsigned int)f2bf(acc2[1]) << 16);
            pk2[nt * 2 + 1] = (unsigned int)f2bf(acc2[2]) | ((unsigned int)f2bf(acc2[3]) << 16);
        }
    }
    __syncthreads();  // all xT B-frag reads done -> safe to overwrite as obuf

#pragma unroll
    for (int nt = 0; nt < 16; ++nt)
#pragma unroll
        for (int r = 0; r < 4; ++r) {
            int row = mb + quad * 4 + r;
            int col = nt * 16 + m16;
            unsigned int v = pk1[nt * 2 + (r >> 1)];
            unsigned short e = (r & 1) ? (unsigned short)(v >> 16) : (unsigned short)(v & 0xffff);
            obuf[row * 256 + (((col >> 3) ^ (row & 7)) * 8) + (col & 7)] = e;
        }
    __syncthreads();
#pragma unroll
    for (int k = 0; k < 8; ++k) {
        int c = k * 256 + tid;
        int row = c >> 5;
        int cg = c & 31;
        uint4 v = *reinterpret_cast<const uint4*>(&obuf[row * 256 + ((cg ^ (row & 7)) * 8)]);
        *reinterpret_cast<uint4*>(&o1b[(size_t)row * HW + hw0 + cg * 8]) = v;
    }

    if (hasw2) {
        __syncthreads();
#pragma unroll
        for (int nt = 0; nt < 16; ++nt)
#pragma unroll
            for (int r = 0; r < 4; ++r) {
                int row = mb + quad * 4 + r;
                int col = nt * 16 + m16;
                unsigned int v = pk2[nt * 2 + (r >> 1)];
                unsigned short e = (r & 1) ? (unsigned short)(v >> 16) : (unsigned short)(v & 0xffff);
                obuf[row * 256 + (((col >> 3) ^ (row & 7)) * 8) + (col & 7)] = e;
            }
        __syncthreads();
#pragma unroll
        for (int k = 0; k < 8; ++k) {
            int c = k * 256 + tid;
            int row = c >> 5;
            int cg = c & 31;
            uint4 v = *reinterpret_cast<const uint4*>(&obuf[row * 256 + ((cg ^ (row & 7)) * 8)]);
            *reinterpret_cast<uint4*>(&o2b[(size_t)row * HW + hw0 + cg * 8]) = v;
        }
    }
}

// ---------------------------------------------------------------------------
// MFMA attention. One block (512 thr = 8 waves) per (b,c).
// LDS: bufP (P), bufB (K then Vt), each 128x128 bf16, XOR-chunk swizzle:
// element (row, k) stored at row*128 + ((k>>3) ^ (row&7))*8 + (k&7).
// Q is loaded DIRECTLY global->A-frags (no LDS staging; 64B/row full-sector).
// mode 0: single branch, write io.
// mode 1: single branch, accumulate into io + stats (fallback path).
// mode 2: dual branch — O1+O2 via chained MFMA accumulator, write io once +
//         stats; branch-2 Q/K loads issued during branch-1 compute.
// ---------------------------------------------------------------------------
__global__ __launch_bounds__(512, 4)
void attn_kernel(const unsigned short* __restrict__ Q1, const unsigned short* __restrict__ K1,
                 const unsigned short* __restrict__ V1,
                 const unsigned short* __restrict__ Q2, const unsigned short* __restrict__ K2,
                 const unsigned short* __restrict__ V2,
                 float* __restrict__ io, float* __restrict__ stats, int mode) {
    __shared__ short bufP[16384];  // 32 KB (P)
    __shared__ short bufB[16384];  // 32 KB (K then Vt)
    int bc = blockIdx.x;
    size_t base = (size_t)bc * HW;
    int tid = threadIdx.x;
    int lane = tid & 63;
    int wv = tid >> 6;         // wave -> row strip [16wv, 16wv+16)
    int quad = lane >> 4;
    int m16 = lane & 15;
    int rowA = wv * 16 + m16;
    int sw = m16 & 7;          // rowA&7 == m16&7
    int g0 = tid >> 4;         // 0..31 (stage row group)
    int c0 = tid & 15;         // stage chunk
    int w0 = c0 * 8;

    // ---- Phase 0: issue V1 preload, K1 stage loads, Q1 direct A-frags ----
    uint4 vreg[4];
#pragma unroll
    for (int i = 0; i < 4; ++i)
        vreg[i] = *(const uint4*)(V1 + base + (size_t)(g0 + 32 * i) * 128 + w0);
    uint4 kst[4];
#pragma unroll
    for (int i = 0; i < 4; ++i)
        kst[i] = *(const uint4*)(K1 + base + (size_t)(g0 + 32 * i) * 128 + w0);
    bf16x8 aF[4];
#pragma unroll
    for (int ks = 0; ks < 4; ++ks)
        aF[ks] = *reinterpret_cast<const bf16x8*>(Q1 + base + (size_t)rowA * 128 + (ks * 4 + quad) * 8);

    // ---- K1 -> bufB (swizzled) ----
#pragma unroll
    for (int i = 0; i < 4; ++i) {
        int r = g0 + 32 * i;
        int ch = c0 ^ (r & 7);
        *reinterpret_cast<uint4*>(&bufB[r * 128 + ch * 8]) = kst[i];
    }
    __syncthreads();  // B1

    // ---- S1 = Q1 K1^T ----
    f32x4 sacc[8];
#pragma unroll
    for (int n = 0; n < 8; ++n) {
        f32x4 acc = {0.f, 0.f, 0.f, 0.f};
        int rowB = n * 16 + m16;
#pragma unroll
        for (int ks = 0; ks < 4; ++ks) {
            int ch = (ks * 4 + quad) ^ sw;
            bf16x8 bF = *reinterpret_cast<const bf16x8*>(&bufB[rowB * 128 + ch * 8]);
            acc = __builtin_amdgcn_mfma_f32_16x16x32_bf16(aF[ks], bF, acc, 0, 0, 0);
        }
        sacc[n] = acc;
    }

    // ---- softmax1 (rows in regs: row = 16wv + quad*4 + r) ----
    const float scale = 0.08838834764831845f;  // 1/sqrt(128)
    {
        float mx[4] = {-3.4e38f, -3.4e38f, -3.4e38f, -3.4e38f};
#pragma unroll
        for (int n = 0; n < 8; ++n)
#pragma unroll
            for (int r = 0; r < 4; ++r) {
                sacc[n][r] *= scale;
                mx[r] = fmaxf(mx[r], sacc[n][r]);
            }
#pragma unroll
        for (int mask = 8; mask >= 1; mask >>= 1)
#pragma unroll
            for (int r = 0; r < 4; ++r) mx[r] = fmaxf(mx[r], __shfl_xor(mx[r], mask));
        float sum[4] = {0.f, 0.f, 0.f, 0.f};
#pragma unroll
        for (int n = 0; n < 8; ++n)
#pragma unroll
            for (int r = 0; r < 4; ++r) {
                float e = __expf(sacc[n][r] - mx[r]);
                sacc[n][r] = e;
                sum[r] += e;
            }
#pragma unroll
        for (int mask = 8; mask >= 1; mask >>= 1)
#pragma unroll
            for (int r = 0; r < 4; ++r) sum[r] += __shfl_xor(sum[r], mask);
#pragma unroll
        for (int n = 0; n < 8; ++n)
#pragma unroll
            for (int r = 0; r < 4; ++r) sacc[n][r] *= 1.0f / sum[r];
    }

    // ---- P1 (bf16) -> bufP (wave-private strip; no barrier needed) ----
#pragma unroll
    for (int n = 0; n < 8; ++n)
#pragma unroll
        for (int r = 0; r < 4; ++r) {
            int row = wv * 16 + quad * 4 + r;
            int col = n * 16 + m16;
            int pos = row * 128 + (((col >> 3) ^ (row & 7)) * 8) + (col & 7);
            bufP[pos] = (short)f2bf(sacc[n][r]);
        }

    __syncthreads();  // B2: all K1 B-frag reads done -> bufB reusable

    // ---- dual: issue branch-2 K stage loads + Q2 direct frags early ----
    bf16x8 qF2[4];
    if (mode == 2) {
#pragma unroll
        for (int i = 0; i < 4; ++i)
            kst[i] = *(const uint4*)(K2 + base + (size_t)(g0 + 32 * i) * 128 + w0);
#pragma unroll
        for (int ks = 0; ks < 4; ++ks)
            qF2[ks] = *reinterpret_cast<const bf16x8*>(Q2 + base + (size_t)rowA * 128 + (ks * 4 + quad) * 8);
    }

    // ---- Vt1 (transposed, swizzled) into bufB from vreg ----
    {
#pragma unroll
        for (int i = 0; i < 4; ++i) {
            int g = g0 + 32 * i;
            unsigned short e[8];
            *(uint4*)e = vreg[i];
#pragma unroll
            for (int jj = 0; jj < 8; ++jj) {
                int j = jj ^ (tid & 7);  // stagger to break bank pile-up
                int w = w0 + j;
                int pos = w * 128 + (((g >> 3) ^ (w & 7)) * 8) + (g & 7);
                bufB[pos] = (short)e[j];
            }
        }
    }
    // ---- dual: issue V2 preload now that vreg is consumed ----
    if (mode == 2) {
#pragma unroll
        for (int i = 0; i < 4; ++i)
            vreg[i] = *(const uint4*)(V2 + base + (size_t)(g0 + 32 * i) * 128 + w0);
    }
    __syncthreads();  // B3

    // ---- O1 = P1 V1 ----
#pragma unroll
    for (int ks = 0; ks < 4; ++ks) {
        int ch = (ks * 4 + quad) ^ sw;
        aF[ks] = *reinterpret_cast<const bf16x8*>(&bufP[rowA * 128 + ch * 8]);
    }
    f32x4 oacc[8];
#pragma unroll
    for (int n = 0; n < 8; ++n) {
        f32x4 acc = {0.f, 0.f, 0.f, 0.f};
        int rowB = n * 16 + m16;
#pragma unroll
        for (int ks = 0; ks < 4; ++ks) {
            int ch = (ks * 4 + quad) ^ sw;
            bf16x8 bF = *reinterpret_cast<const bf16x8*>(&bufB[rowB * 128 + ch * 8]);
            acc = __builtin_amdgcn_mfma_f32_16x16x32_bf16(aF[ks], bF, acc, 0, 0, 0);
        }
        oacc[n] = acc;
    }

    if (mode == 2) {
        __syncthreads();  // B4: all Vt1 B-frag reads done -> bufB reusable
        // ---- K2 -> bufB ----
#pragma unroll
        for (int i = 0; i < 4; ++i) {
            int r = g0 + 32 * i;
            int ch = c0 ^ (r & 7);
            *reinterpret_cast<uint4*>(&bufB[r * 128 + ch * 8]) = kst[i];
        }
        __syncthreads();  // B5

        // ---- S2 = Q2 K2^T ----
#pragma unroll
        for (int n = 0; n < 8; ++n) {
            f32x4 acc = {0.f, 0.f, 0.f, 0.f};
            int rowB = n * 16 + m16;
#pragma unroll
            for (int ks = 0; ks < 4; ++ks) {
                int ch = (ks * 4 + quad) ^ sw;
                bf16x8 bF = *reinterpret_cast<const bf16x8*>(&bufB[rowB * 128 + ch * 8]);
                acc = __builtin_amdgcn_mfma_f32_16x16x32_bf16(qF2[ks], bF, acc, 0, 0, 0);
            }
            sacc[n] = acc;
        }

        // ---- softmax2 ----
        {
            float mx[4] = {-3.4e38f, -3.4e38f, -3.4e38f, -3.4e38f};
#pragma unroll
            for (int n = 0; n < 8; ++n)
#pragma unroll
                for (int r = 0; r < 4; ++r) {
                    sacc[n][r] *= scale;
                    mx[r] = fmaxf(mx[r], sacc[n][r]);
                }
#pragma unroll
            for (int mask = 8; mask >= 1; mask >>= 1)
#pragma unroll
                for (int r = 0; r < 4; ++r) mx[r] = fmaxf(mx[r], __shfl_xor(mx[r], mask));
            float sum[4] = {0.f, 0.f, 0.f, 0.f};
#pragma unroll
            for (int n = 0; n < 8; ++n)
#pragma unroll
                for (int r = 0; r < 4; ++r) {
                    float e = __expf(sacc[n][r] - mx[r]);
                    sacc[n][r] = e;
                    sum[r] += e;
                }
#pragma unroll
            for (int mask = 8; mask >= 1; mask >>= 1)
#pragma unroll
                for (int r = 0; r < 4; ++r) sum[r] += __shfl_xor(sum[r], mask);
#pragma unroll
            for (int n = 0; n < 8; ++n)
#pragma unroll
                for (int r = 0; r < 4; ++r) sacc[n][r] *= 1.0f / sum[r];
        }

        // ---- P2 -> bufP (own strip; own PV1 A-frags already loaded) ----
#pragma unroll
        for (int n = 0; n < 8; ++n)
#pragma unroll
            for (int r = 0; r < 4; ++r) {
                int row = wv * 16 + quad * 4 + r;
                int col = n * 16 + m16;
                int pos = row * 128 + (((col >> 3) ^ (row & 7)) * 8) + (col & 7);
                bufP[pos] = (short)f2bf(sacc[n][r]);
            }
        __syncthreads();  // B6: all K2 B-frag reads done

        // ---- Vt2 -> bufB ----
#pragma unroll
        for (int i = 0; i < 4; ++i) {
            int g = g0 + 32 * i;
            unsigned short e[8];
            *(uint4*)e = vreg[i];
#pragma unroll
            for (int jj = 0; jj < 8; ++jj) {
                int j = jj ^ (tid & 7);
                int w = w0 + j;
                int pos = w * 128 + (((g >> 3) ^ (w & 7)) * 8) + (g & 7);
                bufB[pos] = (short)e[j];
            }
        }
        __syncthreads();  // B7

        // ---- O += P2 V2 (chained accumulator) ----
#pragma unroll
        for (int ks = 0; ks < 4; ++ks) {
            int ch = (ks * 4 + quad) ^ sw;
            aF[ks] = *reinterpret_cast<const bf16x8*>(&bufP[rowA * 128 + ch * 8]);
        }
#pragma unroll
        for (int n = 0; n < 8; ++n) {
            f32x4 acc = oacc[n];
            int rowB = n * 16 + m16;
#pragma unroll
            for (int ks = 0; ks < 4; ++ks) {
                int ch = (ks * 4 + quad) ^ sw;
                bf16x8 bF = *reinterpret_cast<const bf16x8*>(&bufB[rowB * 128 + ch * 8]);
                acc = __builtin_amdgcn_mfma_f32_16x16x32_bf16(aF[ks], bF, acc, 0, 0, 0);
            }
            oacc[n] = acc;
        }
    }

    // ---- epilogue: C layout row = 16wv + quad*4 + r, col = 16n + m16 ----
    if (mode == 0) {
#pragma unroll
        for (int n = 0; n < 8; ++n)
#pragma unroll
            for (int r = 0; r < 4; ++r) {
                int row = wv * 16 + quad * 4 + r;
                int col = n * 16 + m16;
                io[base + row * 128 + col] = oacc[n][r];
            }
    } else {
        float lsum = 0.f, lsq = 0.f;
#pragma unroll
        for (int n = 0; n < 8; ++n)
#pragma unroll
            for (int r = 0; r < 4; ++r) {
                int row = wv * 16 + quad * 4 + r;
                int col = n * 16 + m16;
                size_t idx = base + row * 128 + col;
                float f = oacc[n][r];
                if (mode == 1) f += io[idx];
                io[idx] = f;
                lsum += f;
                lsq += f * f;
            }
#pragma unroll
        for (int mask = 32; mask >= 1; mask >>= 1) {
            lsum += __shfl_xor(lsum, mask);
            lsq  += __shfl_xor(lsq,  mask);
        }
        if (lane == 0) {
            int c = bc & 63;
            atomicAdd(&stats[c], lsum);
            atomicAdd(&stats[64 + c], lsq);
        }
    }
}

// in-place fp32: io = relu((io - mean) * rsqrt(var+eps) * gamma + beta)
__global__ __launch_bounds__(256)
void bn_relu_kernel(float* __restrict__ io, const float* __restrict__ stats,
                    const float* __restrict__ gamma, const float* __restrict__ beta) {
    int idx = blockIdx.x * 256 + threadIdx.x;
    int e = idx << 2;
    int c = (e >> 14) & 63;
    const float invN = 1.0f / 262144.0f;
    float mean = stats[c] * invN;
    float var = stats[64 + c] * invN - mean * mean;
    float k = rsqrtf(var + 1e-5f) * gamma[c];
    float bb = beta[c] - mean * k;
    float4 f = reinterpret_cast<const float4*>(io)[idx];
    float4 o;
    o.x = fmaxf(f.x * k + bb, 0.f);
    o.y = fmaxf(f.y * k + bb, 0.f);
    o.z = fmaxf(f.z * k + bb, 0.f);
    o.w = fmaxf(f.w * k + bb, 0.f);
    reinterpret_cast<float4*>(io)[idx] = o;
}

extern "C" void kernel_launch(void* const* d_in, const int* in_sizes, int n_in,
                              void* d_out, int out_size, void* d_ws, size_t ws_size,
                              hipStream_t stream) {
    const float* x1 = (const float*)d_in[0];
    const float* x2 = (const float*)d_in[1];
    const float* rssi1 = (const float*)d_in[2];
    const float* rssi2 = (const float*)d_in[3];
    const float* qw = (const float*)d_in[4];
    const float* qb = (const float*)d_in[5];
    const float* kw = (const float*)d_in[6];
    const float* kb = (const float*)d_in[7];
    const float* vw = (const float*)d_in[8];
    const float* vb = (const float*)d_in[9];
    const float* gamma = (const float*)d_in[10];
    const float* beta = (const float*)d_in[11];

    float* stats = (float*)d_ws;
    unsigned short* Q1 = (unsigned short*)((char*)d_ws + 512);
    unsigned short* K1 = Q1 + NE;
    unsigned short* V1 = K1 + NE;
    float* io = (float*)d_out;

    const size_t need_dual = 512 + 6 * NE * 2;  // 6 QKV buffers + stats

    if (ws_size >= need_dual) {
        unsigned short* Q2 = V1 + NE;
        unsigned short* K2 = Q2 + NE;
        unsigned short* V2 = K2 + NE;
        // all 4 proj jobs in one dispatch; single dual-branch attention
        proj_mfma_kernel<<<4096, 256, 0, stream>>>(rssi1, x1, rssi2, x2,
                                                   qw, qb, kw, kb, vw, vb,
                                                   Q1, K1, V1, Q2, K2, V2, stats);
        attn_kernel<<<1024, 512, 0, stream>>>(Q1, K1, V1, Q2, K2, V2, io, stats, 2);
    } else {
        // fallback: 3-buffer workspace, per-branch dispatches
        proj_mfma_kernel<<<2048, 256, 0, stream>>>(rssi1, x1, nullptr, nullptr,
                                                   qw, qb, kw, kb, vw, vb,
                                                   Q1, K1, V1, nullptr, nullptr, nullptr, stats);
        attn_kernel<<<1024, 512, 0, stream>>>(Q1, K1, V1, nullptr, nullptr, nullptr, io, stats, 0);
        proj_mfma_kernel<<<2048, 256, 0, stream>>>(rssi2, x2, nullptr, nullptr,
                                                   qw, qb, kw, kb, vw, vb,
                                                   Q1, K1, V1, nullptr, nullptr, nullptr, nullptr);
        attn_kernel<<<1024, 512, 0, stream>>>(Q1, K1, V1, nullptr, nullptr, nullptr, io, stats, 1);
    }

    bn_relu_kernel<<<16384, 256, 0, stream>>>(io, stats, gamma, beta);
}

// Round 4
// 442.672 us; speedup vs baseline: 1.0085x; 1.0085x over previous
//
#include <hip/hip_runtime.h>

// Problem constants: B=16, C=64, H=128, W=128, bchw layout, HW = 16384
// Output: fp32. Q/K/V staged as bf16 in ws. Attention via mfma_f32_16x16x32_bf16.
// Projections via mfma_f32_16x16x32_f16 (fp16 inputs, fp32 accum).
// R4: dual-branch attn kept, but branch-2 prefetches restaged so peak live
// registers fit the 128/thread budget at (512,4) -> no scratch spills
// (R3 showed 215 MB of spill WRITE traffic from over-eager prefetch).
#define HW 16384
#define NE 16777216ull   // B*C*H*W

typedef short bf16x8 __attribute__((ext_vector_type(8)));
typedef _Float16 f16x8 __attribute__((ext_vector_type(8)));
typedef float f32x4  __attribute__((ext_vector_type(4)));

__device__ __forceinline__ unsigned short f2bf(float f) {
    unsigned int u = __float_as_uint(f);
    unsigned int r = (u + 0x7FFFu + ((u >> 16) & 1u)) >> 16;  // RNE
    return (unsigned short)r;
}

// ---------------------------------------------------------------------------
// Mega projection dispatch. Grid = njobs*1024 blocks; job = blockIdx.x>>10:
//   job 0: rA -> (qw,qb) -> QA            job 2: rB -> (qw,qb) -> QB
//   job 1: xA -> (kw,kb)->KA, (vw,vb)->VA job 3: xB -> (kw,kb)->KB, (vw,vb)->VB
// One block = one b, 256-wide hw tile; 256 threads = 4 waves.
// LDS xT[n][c] fp16 (transposed input tile), XOR-chunk swizzled; reused as
// obuf[64][256] bf16 for the coalesced dwordx4 store epilogue.
// Block 0 zeroes stats[0..127] when stats != null.
// ---------------------------------------------------------------------------
__global__ __launch_bounds__(256)
void proj_mfma_kernel(const float* __restrict__ rA, const float* __restrict__ xA,
                      const float* __restrict__ rB, const float* __restrict__ xB,
                      const float* __restrict__ qw, const float* __restrict__ qb,
                      const float* __restrict__ kw, const float* __restrict__ kb,
                      const float* __restrict__ vw, const float* __restrict__ vb,
                      unsigned short* __restrict__ QA, unsigned short* __restrict__ KA,
                      unsigned short* __restrict__ VA,
                      unsigned short* __restrict__ QB, unsigned short* __restrict__ KB,
                      unsigned short* __restrict__ VB,
                      float* __restrict__ stats) {
    __shared__ __align__(16) _Float16 xT[256 * 64];  // 32 KB
    unsigned short* obuf = reinterpret_cast<unsigned short*>(xT);
    int tid = threadIdx.x;
    if (stats != nullptr && blockIdx.x == 0 && tid < 128) stats[tid] = 0.f;

    int job = blockIdx.x >> 10;
    const float *in, *w1, *b1, *w2 = nullptr, *b2 = nullptr;
    unsigned short *o1, *o2 = nullptr;
    if (job == 0)      { in = rA; w1 = qw; b1 = qb; o1 = QA; }
    else if (job == 1) { in = xA; w1 = kw; b1 = kb; o1 = KA; w2 = vw; b2 = vb; o2 = VA; }
    else if (job == 2) { in = rB; w1 = qw; b1 = qb; o1 = QB; }
    else               { in = xB; w1 = kw; b1 = kb; o1 = KB; w2 = vw; b2 = vb; o2 = VB; }

    int pbase = (blockIdx.x & 1023) * 256;
    int b = pbase >> 14;
    int hw0 = pbase & 16383;
    const float* inb = in + (size_t)b * (64 * HW);

    // ---- stage transposed tile: thread t owns column n = t ----
    {
        int n = tid;
        int swz = n & 7;
        const float* colp = inb + hw0 + n;
#pragma unroll
        for (int kc = 0; kc < 8; ++kc) {
            f16x8 ev;
#pragma unroll
            for (int j = 0; j < 8; ++j)
                ev[j] = (_Float16)colp[(kc * 8 + j) * HW];
            *reinterpret_cast<f16x8*>(&xT[n * 64 + ((kc ^ swz) * 8)]) = ev;
        }
    }

    int lane = tid & 63;
    int wv = tid >> 6;
    int quad = lane >> 4;
    int m16 = lane & 15;
    int mb = wv * 16;
    int sw = m16 & 7;
    int hasw2 = (w2 != nullptr);

    // ---- A-frags (weights, fp16) + bias (overlaps with staging latency) ----
    f16x8 a1[2], a2[2];
    float bias1[4], bias2[4];
#pragma unroll
    for (int ks = 0; ks < 2; ++ks) {
        const float* wr = w1 + (mb + m16) * 64 + (ks * 4 + quad) * 8;
        f16x8 ev;
#pragma unroll
        for (int j = 0; j < 8; ++j) ev[j] = (_Float16)wr[j];
        a1[ks] = ev;
    }
#pragma unroll
    for (int r = 0; r < 4; ++r) bias1[r] = b1[mb + quad * 4 + r];
    if (hasw2) {
#pragma unroll
        for (int ks = 0; ks < 2; ++ks) {
            const float* wr = w2 + (mb + m16) * 64 + (ks * 4 + quad) * 8;
            f16x8 ev;
#pragma unroll
            for (int j = 0; j < 8; ++j) ev[j] = (_Float16)wr[j];
            a2[ks] = ev;
        }
#pragma unroll
        for (int r = 0; r < 4; ++r) bias2[r] = b2[mb + quad * 4 + r];
    }
    __syncthreads();

    unsigned short* o1b = o1 + (size_t)b * (64 * HW);
    unsigned short* o2b = hasw2 ? (o2 + (size_t)b * (64 * HW)) : o1b;

    // ---- D[o][n] = sum_c W[o][c] * xT[n][c]; results packed to bf16 pairs ----
    unsigned int pk1[32], pk2[32];
#pragma unroll
    for (int nt = 0; nt < 16; ++nt) {
        int row = nt * 16 + m16;
        f16x8 bF0 = *reinterpret_cast<const f16x8*>(&xT[row * 64 + ((quad ^ sw) * 8)]);
        f16x8 bF1 = *reinterpret_cast<const f16x8*>(&xT[row * 64 + (((4 + quad) ^ sw) * 8)]);
        f32x4 acc1 = {bias1[0], bias1[1], bias1[2], bias1[3]};
        acc1 = __builtin_amdgcn_mfma_f32_16x16x32_f16(a1[0], bF0, acc1, 0, 0, 0);
        acc1 = __builtin_amdgcn_mfma_f32_16x16x32_f16(a1[1], bF1, acc1, 0, 0, 0);
        pk1[nt * 2 + 0] = (unsigned int)f2bf(acc1[0]) | ((unsigned int)f2bf(acc1[1]) << 16);
        pk1[nt * 2 + 1] = (unsigned int)f2bf(acc1[2]) | ((unsigned int)f2bf(acc1[3]) << 16);
        if (hasw2) {
            f32x4 acc2 = {bias2[0], bias2[1], bias2[2], bias2[3]};
            acc2 = __builtin_amdgcn_mfma_f32_16x16x32_f16(a2[0], bF0, acc2, 0, 0, 0);
            acc2 = __builtin_amdgcn_mfma_f32_16x16x32_f16(a2[1], bF1, acc2, 0, 0, 0);
            pk2[nt * 2 + 0] = (unsigned int)f2bf(acc2[0]) | ((unsigned int)f2bf(acc2[1]) << 16);
            pk2[nt * 2 + 1] = (unsigned int)f2bf(acc2[2]) | ((unsigned int)f2bf(acc2[3]) << 16);
        }
    }
    __syncthreads();  // all xT B-frag reads done -> safe to overwrite as obuf

#pragma unroll
    for (int nt = 0; nt < 16; ++nt)
#pragma unroll
        for (int r = 0; r < 4; ++r) {
            int row = mb + quad * 4 + r;
            int col = nt * 16 + m16;
            unsigned int v = pk1[nt * 2 + (r >> 1)];
            unsigned short e = (r & 1) ? (unsigned short)(v >> 16) : (unsigned short)(v & 0xffff);
            obuf[row * 256 + (((col >> 3) ^ (row & 7)) * 8) + (col & 7)] = e;
        }
    __syncthreads();
#pragma unroll
    for (int k = 0; k < 8; ++k) {
        int c = k * 256 + tid;
        int row = c >> 5;
        int cg = c & 31;
        uint4 v = *reinterpret_cast<const uint4*>(&obuf[row * 256 + ((cg ^ (row & 7)) * 8)]);
        *reinterpret_cast<uint4*>(&o1b[(size_t)row * HW + hw0 + cg * 8]) = v;
    }

    if (hasw2) {
        __syncthreads();
#pragma unroll
        for (int nt = 0; nt < 16; ++nt)
#pragma unroll
            for (int r = 0; r < 4; ++r) {
                int row = mb + quad * 4 + r;
                int col = nt * 16 + m16;
                unsigned int v = pk2[nt * 2 + (r >> 1)];
                unsigned short e = (r & 1) ? (unsigned short)(v >> 16) : (unsigned short)(v & 0xffff);
                obuf[row * 256 + (((col >> 3) ^ (row & 7)) * 8) + (col & 7)] = e;
            }
        __syncthreads();
#pragma unroll
        for (int k = 0; k < 8; ++k) {
            int c = k * 256 + tid;
            int row = c >> 5;
            int cg = c & 31;
            uint4 v = *reinterpret_cast<const uint4*>(&obuf[row * 256 + ((cg ^ (row & 7)) * 8)]);
            *reinterpret_cast<uint4*>(&o2b[(size_t)row * HW + hw0 + cg * 8]) = v;
        }
    }
}

// ---------------------------------------------------------------------------
// MFMA attention. One block (512 thr = 8 waves) per (b,c).
// LDS: bufP (P), bufB (K then Vt), each 128x128 bf16, XOR-chunk swizzle:
// element (row, k) stored at row*128 + ((k>>3) ^ (row&7))*8 + (k&7).
// Q is loaded DIRECTLY global->A-frags (no LDS staging).
// mode 0: single branch, write io.
// mode 1: single branch, accumulate into io + stats (fallback path).
// mode 2: dual branch — O1+O2 via chained MFMA accumulator, io written once.
//         Branch-2 loads are issued only where the source registers are dead
//         (kst after B2, vreg after the Vt1 scatter, Q2 after PV1) so peak
//         live VGPR+AGPR stays <= 128 (no scratch spill).
// ---------------------------------------------------------------------------
__global__ __launch_bounds__(512, 4)
void attn_kernel(const unsigned short* __restrict__ Q1, const unsigned short* __restrict__ K1,
                 const unsigned short* __restrict__ V1,
                 const unsigned short* __restrict__ Q2, const unsigned short* __restrict__ K2,
                 const unsigned short* __restrict__ V2,
                 float* __restrict__ io, float* __restrict__ stats, int mode) {
    __shared__ short bufP[16384];  // 32 KB (P)
    __shared__ short bufB[16384];  // 32 KB (K then Vt)
    int bc = blockIdx.x;
    size_t base = (size_t)bc * HW;
    int tid = threadIdx.x;
    int lane = tid & 63;
    int wv = tid >> 6;         // wave -> row strip [16wv, 16wv+16)
    int quad = lane >> 4;
    int m16 = lane & 15;
    int rowA = wv * 16 + m16;
    int sw = m16 & 7;          // rowA&7 == m16&7
    int g0 = tid >> 4;         // 0..31 (stage row group)
    int c0 = tid & 15;         // stage chunk
    int w0 = c0 * 8;
    const float scale = 0.08838834764831845f;  // 1/sqrt(128)

    // ---- Phase 0: V1 preload, K1 stage loads, Q1 direct A-frags ----
    uint4 vreg[4];
#pragma unroll
    for (int i = 0; i < 4; ++i)
        vreg[i] = *(const uint4*)(V1 + base + (size_t)(g0 + 32 * i) * 128 + w0);
    {
        uint4 kst[4];
#pragma unroll
        for (int i = 0; i < 4; ++i)
            kst[i] = *(const uint4*)(K1 + base + (size_t)(g0 + 32 * i) * 128 + w0);
#pragma unroll
        for (int i = 0; i < 4; ++i) {
            int r = g0 + 32 * i;
            int ch = c0 ^ (r & 7);
            *reinterpret_cast<uint4*>(&bufB[r * 128 + ch * 8]) = kst[i];
        }
    }
    bf16x8 aF[4];
#pragma unroll
    for (int ks = 0; ks < 4; ++ks)
        aF[ks] = *reinterpret_cast<const bf16x8*>(Q1 + base + (size_t)rowA * 128 + (ks * 4 + quad) * 8);
    __syncthreads();  // B1

    // ---- S1 = Q1 K1^T ----
    f32x4 sacc[8];
#pragma unroll
    for (int n = 0; n < 8; ++n) {
        f32x4 acc = {0.f, 0.f, 0.f, 0.f};
        int rowB = n * 16 + m16;
#pragma unroll
        for (int ks = 0; ks < 4; ++ks) {
            int ch = (ks * 4 + quad) ^ sw;
            bf16x8 bF = *reinterpret_cast<const bf16x8*>(&bufB[rowB * 128 + ch * 8]);
            acc = __builtin_amdgcn_mfma_f32_16x16x32_bf16(aF[ks], bF, acc, 0, 0, 0);
        }
        sacc[n] = acc;
    }

    // ---- softmax1 (rows in regs: row = 16wv + quad*4 + r) ----
    {
        float mx[4] = {-3.4e38f, -3.4e38f, -3.4e38f, -3.4e38f};
#pragma unroll
        for (int n = 0; n < 8; ++n)
#pragma unroll
            for (int r = 0; r < 4; ++r) {
                sacc[n][r] *= scale;
                mx[r] = fmaxf(mx[r], sacc[n][r]);
            }
#pragma unroll
        for (int mask = 8; mask >= 1; mask >>= 1)
#pragma unroll
            for (int r = 0; r < 4; ++r) mx[r] = fmaxf(mx[r], __shfl_xor(mx[r], mask));
        float sum[4] = {0.f, 0.f, 0.f, 0.f};
#pragma unroll
        for (int n = 0; n < 8; ++n)
#pragma unroll
            for (int r = 0; r < 4; ++r) {
                float e = __expf(sacc[n][r] - mx[r]);
                sacc[n][r] = e;
                sum[r] += e;
            }
#pragma unroll
        for (int mask = 8; mask >= 1; mask >>= 1)
#pragma unroll
            for (int r = 0; r < 4; ++r) sum[r] += __shfl_xor(sum[r], mask);
#pragma unroll
        for (int n = 0; n < 8; ++n)
#pragma unroll
            for (int r = 0; r < 4; ++r) sacc[n][r] *= 1.0f / sum[r];
    }

    // ---- P1 (bf16) -> bufP (wave-private strip; no barrier needed) ----
#pragma unroll
    for (int n = 0; n < 8; ++n)
#pragma unroll
        for (int r = 0; r < 4; ++r) {
            int row = wv * 16 + quad * 4 + r;
            int col = n * 16 + m16;
            int pos = row * 128 + (((col >> 3) ^ (row & 7)) * 8) + (col & 7);
            bufP[pos] = (short)f2bf(sacc[n][r]);
        }

    __syncthreads();  // B2: all K1 B-frag reads done -> bufB reusable

    // ---- dual: issue K2 loads now (kst dead since phase 0; hides under
    //      Vt1 scatter + B3 + PV1) ----
    uint4 kst2[4];
    if (mode == 2) {
#pragma unroll
        for (int i = 0; i < 4; ++i)
            kst2[i] = *(const uint4*)(K2 + base + (size_t)(g0 + 32 * i) * 128 + w0);
    }

    // ---- Vt1 (transposed, swizzled) into bufB from vreg ----
#pragma unroll
    for (int i = 0; i < 4; ++i) {
        int g = g0 + 32 * i;
        unsigned short e[8];
        *(uint4*)e = vreg[i];
#pragma unroll
        for (int jj = 0; jj < 8; ++jj) {
            int j = jj ^ (tid & 7);  // stagger to break bank pile-up
            int w = w0 + j;
            int pos = w * 128 + (((g >> 3) ^ (w & 7)) * 8) + (g & 7);
            bufB[pos] = (short)e[j];
        }
    }
    // ---- dual: vreg now dead -> issue V2 preload (hides under PV1+S2) ----
    if (mode == 2) {
#pragma unroll
        for (int i = 0; i < 4; ++i)
            vreg[i] = *(const uint4*)(V2 + base + (size_t)(g0 + 32 * i) * 128 + w0);
    }
    __syncthreads();  // B3

    // ---- O1 = P1 V1 ----
#pragma unroll
    for (int ks = 0; ks < 4; ++ks) {
        int ch = (ks * 4 + quad) ^ sw;
        aF[ks] = *reinterpret_cast<const bf16x8*>(&bufP[rowA * 128 + ch * 8]);
    }
    f32x4 oacc[8];
#pragma unroll
    for (int n = 0; n < 8; ++n) {
        f32x4 acc = {0.f, 0.f, 0.f, 0.f};
        int rowB = n * 16 + m16;
#pragma unroll
        for (int ks = 0; ks < 4; ++ks) {
            int ch = (ks * 4 + quad) ^ sw;
            bf16x8 bF = *reinterpret_cast<const bf16x8*>(&bufB[rowB * 128 + ch * 8]);
            acc = __builtin_amdgcn_mfma_f32_16x16x32_bf16(aF[ks], bF, acc, 0, 0, 0);
        }
        oacc[n] = acc;
    }

    if (mode == 2) {
        __syncthreads();  // B4: all Vt1 B-frag reads done -> bufB reusable
        // ---- K2 -> bufB (from kst2, already in flight since B2) ----
#pragma unroll
        for (int i = 0; i < 4; ++i) {
            int r = g0 + 32 * i;
            int ch = c0 ^ (r & 7);
            *reinterpret_cast<uint4*>(&bufB[r * 128 + ch * 8]) = kst2[i];
        }
        // ---- Q2 direct frags (aF dead after PV1; latency hides under B5) ----
#pragma unroll
        for (int ks = 0; ks < 4; ++ks)
            aF[ks] = *reinterpret_cast<const bf16x8*>(Q2 + base + (size_t)rowA * 128 + (ks * 4 + quad) * 8);
        __syncthreads();  // B5

        // ---- S2 = Q2 K2^T ----
#pragma unroll
        for (int n = 0; n < 8; ++n) {
            f32x4 acc = {0.f, 0.f, 0.f, 0.f};
            int rowB = n * 16 + m16;
#pragma unroll
            for (int ks = 0; ks < 4; ++ks) {
                int ch = (ks * 4 + quad) ^ sw;
                bf16x8 bF = *reinterpret_cast<const bf16x8*>(&bufB[rowB * 128 + ch * 8]);
                acc = __builtin_amdgcn_mfma_f32_16x16x32_bf16(aF[ks], bF, acc, 0, 0, 0);
            }
            sacc[n] = acc;
        }

        // ---- softmax2 ----
        {
            float mx[4] = {-3.4e38f, -3.4e38f, -3.4e38f, -3.4e38f};
#pragma unroll
            for (int n = 0; n < 8; ++n)
#pragma unroll
                for (int r = 0; r < 4; ++r) {
                    sacc[n][r] *= scale;
                    mx[r] = fmaxf(mx[r], sacc[n][r]);
                }
#pragma unroll
            for (int mask = 8; mask >= 1; mask >>= 1)
#pragma unroll
                for (int r = 0; r < 4; ++r) mx[r] = fmaxf(mx[r], __shfl_xor(mx[r], mask));
            float sum[4] = {0.f, 0.f, 0.f, 0.f};
#pragma unroll
            for (int n = 0; n < 8; ++n)
#pragma unroll
                for (int r = 0; r < 4; ++r) {
                    float e = __expf(sacc[n][r] - mx[r]);
                    sacc[n][r] = e;
                    sum[r] += e;
                }
#pragma unroll
            for (int mask = 8; mask >= 1; mask >>= 1)
#pragma unroll
                for (int r = 0; r < 4; ++r) sum[r] += __shfl_xor(sum[r], mask);
#pragma unroll
            for (int n = 0; n < 8; ++n)
#pragma unroll
                for (int r = 0; r < 4; ++r) sacc[n][r] *= 1.0f / sum[r];
        }

        // ---- P2 -> bufP (own strip; P1 own-strip reads are done) ----
#pragma unroll
        for (int n = 0; n < 8; ++n)
#pragma unroll
            for (int r = 0; r < 4; ++r) {
                int row = wv * 16 + quad * 4 + r;
                int col = n * 16 + m16;
                int pos = row * 128 + (((col >> 3) ^ (row & 7)) * 8) + (col & 7);
                bufP[pos] = (short)f2bf(sacc[n][r]);
            }
        __syncthreads();  // B6: all K2 B-frag reads done

        // ---- Vt2 -> bufB ----
#pragma unroll
        for (int i = 0; i < 4; ++i) {
            int g = g0 + 32 * i;
            unsigned short e[8];
            *(uint4*)e = vreg[i];
#pragma unroll
            for (int jj = 0; jj < 8; ++jj) {
                int j = jj ^ (tid & 7);
                int w = w0 + j;
                int pos = w * 128 + (((g >> 3) ^ (w & 7)) * 8) + (g & 7);
                bufB[pos] = (short)e[j];
            }
        }
        __syncthreads();  // B7

        // ---- O += P2 V2 (chained accumulator) ----
#pragma unroll
        for (int ks = 0; ks < 4; ++ks) {
            int ch = (ks * 4 + quad) ^ sw;
            aF[ks] = *reinterpret_cast<const bf16x8*>(&bufP[rowA * 128 + ch * 8]);
        }
#pragma unroll
        for (int n = 0; n < 8; ++n) {
            f32x4 acc = oacc[n];
            int rowB = n * 16 + m16;
#pragma unroll
            for (int ks = 0; ks < 4; ++ks) {
                int ch = (ks * 4 + quad) ^ sw;
                bf16x8 bF = *reinterpret_cast<const bf16x8*>(&bufB[rowB * 128 + ch * 8]);
                acc = __builtin_amdgcn_mfma_f32_16x16x32_bf16(aF[ks], bF, acc, 0, 0, 0);
            }
            oacc[n] = acc;
        }
    }

    // ---- epilogue: C layout row = 16wv + quad*4 + r, col = 16n + m16 ----
    if (mode == 0) {
#pragma unroll
        for (int n = 0; n < 8; ++n)
#pragma unroll
            for (int r = 0; r < 4; ++r) {
                int row = wv * 16 + quad * 4 + r;
                int col = n * 16 + m16;
                io[base + row * 128 + col] = oacc[n][r];
            }
    } else {
        float lsum = 0.f, lsq = 0.f;
#pragma unroll
        for (int n = 0; n < 8; ++n)
#pragma unroll
            for (int r = 0; r < 4; ++r) {
                int row = wv * 16 + quad * 4 + r;
                int col = n * 16 + m16;
                size_t idx = base + row * 128 + col;
                float f = oacc[n][r];
                if (mode == 1) f += io[idx];
                io[idx] = f;
                lsum += f;
                lsq += f * f;
            }
#pragma unroll
        for (int mask = 32; mask >= 1; mask >>= 1) {
            lsum += __shfl_xor(lsum, mask);
            lsq  += __shfl_xor(lsq,  mask);
        }
        if (lane == 0) {
            int c = bc & 63;
            atomicAdd(&stats[c], lsum);
            atomicAdd(&stats[64 + c], lsq);
        }
    }
}

// in-place fp32: io = relu((io - mean) * rsqrt(var+eps) * gamma + beta)
__global__ __launch_bounds__(256)
void bn_relu_kernel(float* __restrict__ io, const float* __restrict__ stats,
                    const float* __restrict__ gamma, const float* __restrict__ beta) {
    int idx = blockIdx.x * 256 + threadIdx.x;
    int e = idx << 2;
    int c = (e >> 14) & 63;
    const float invN = 1.0f / 262144.0f;
    float mean = stats[c] * invN;
    float var = stats[64 + c] * invN - mean * mean;
    float k = rsqrtf(var + 1e-5f) * gamma[c];
    float bb = beta[c] - mean * k;
    float4 f = reinterpret_cast<const float4*>(io)[idx];
    float4 o;
    o.x = fmaxf(f.x * k + bb, 0.f);
    o.y = fmaxf(f.y * k + bb, 0.f);
    o.z = fmaxf(f.z * k + bb, 0.f);
    o.w = fmaxf(f.w * k + bb, 0.f);
    reinterpret_cast<float4*>(io)[idx] = o;
}

extern "C" void kernel_launch(void* const* d_in, const int* in_sizes, int n_in,
                              void* d_out, int out_size, void* d_ws, size_t ws_size,
                              hipStream_t stream) {
    const float* x1 = (const float*)d_in[0];
    const float* x2 = (const float*)d_in[1];
    const float* rssi1 = (const float*)d_in[2];
    const float* rssi2 = (const float*)d_in[3];
    const float* qw = (const float*)d_in[4];
    const float* qb = (const float*)d_in[5];
    const float* kw = (const float*)d_in[6];
    const float* kb = (const float*)d_in[7];
    const float* vw = (const float*)d_in[8];
    const float* vb = (const float*)d_in[9];
    const float* gamma = (const float*)d_in[10];
    const float* beta = (const float*)d_in[11];

    float* stats = (float*)d_ws;
    unsigned short* Q1 = (unsigned short*)((char*)d_ws + 512);
    unsigned short* K1 = Q1 + NE;
    unsigned short* V1 = K1 + NE;
    float* io = (float*)d_out;

    const size_t need_dual = 512 + 6 * NE * 2;  // 6 QKV buffers + stats

    if (ws_size >= need_dual) {
        unsigned short* Q2 = V1 + NE;
        unsigned short* K2 = Q2 + NE;
        unsigned short* V2 = K2 + NE;
        // all 4 proj jobs in one dispatch; single dual-branch attention
        proj_mfma_kernel<<<4096, 256, 0, stream>>>(rssi1, x1, rssi2, x2,
                                                   qw, qb, kw, kb, vw, vb,
                                                   Q1, K1, V1, Q2, K2, V2, stats);
        attn_kernel<<<1024, 512, 0, stream>>>(Q1, K1, V1, Q2, K2, V2, io, stats, 2);
    } else {
        // fallback: 3-buffer workspace, per-branch dispatches
        proj_mfma_kernel<<<2048, 256, 0, stream>>>(rssi1, x1, nullptr, nullptr,
                                                   qw, qb, kw, kb, vw, vb,
                                                   Q1, K1, V1, nullptr, nullptr, nullptr, stats);
        attn_kernel<<<1024, 512, 0, stream>>>(Q1, K1, V1, nullptr, nullptr, nullptr, io, stats, 0);
        proj_mfma_kernel<<<2048, 256, 0, stream>>>(rssi2, x2, nullptr, nullptr,
                                                   qw, qb, kw, kb, vw, vb,
                                                   Q1, K1, V1, nullptr, nullptr, nullptr, nullptr);
        attn_kernel<<<1024, 512, 0, stream>>>(Q1, K1, V1, nullptr, nullptr, nullptr, io, stats, 1);
    }

    bn_relu_kernel<<<16384, 256, 0, stream>>>(io, stats, gamma, beta);
}